// Round 17
// baseline (398.196 us; speedup 1.0000x reference)
//
#include <hip/hip_runtime.h>
#include <hip/hip_bf16.h>
#include <stdint.h>

typedef __attribute__((ext_vector_type(8))) short bf16x8;
typedef __attribute__((ext_vector_type(4))) float f32x4;
typedef __attribute__((ext_vector_type(4))) short s16x4;
typedef __attribute__((address_space(3))) char lds_char_t;

#define LOG2E_X2 2.885390081777927f
#define GIF_A 5.770780163555854f  // 4*log2(e)

__device__ __forceinline__ float fexp2(float x) { return __builtin_amdgcn_exp2f(x); }
__device__ __forceinline__ float frcp(float x)  { return __builtin_amdgcn_rcpf(x); }
__device__ __forceinline__ float gif_spike(float v) {
  return frcp(1.f + fexp2(fmaf(v, -GIF_A, GIF_A)));
}
__device__ __forceinline__ float fsig(float x)  { return frcp(1.f + fexp2(-1.442695040888963f * x)); }
__device__ __forceinline__ float ftanh(float x) { return 1.f - 2.f * frcp(1.f + fexp2(LOG2E_X2 * x)); }
__device__ __forceinline__ float b2f(unsigned short u) {
  return __uint_as_float((unsigned)u << 16);
}

__device__ __forceinline__ void gload_lds16(const void* g, void* l) {
  __builtin_amdgcn_global_load_lds((__attribute__((address_space(1))) void*)(uintptr_t)g,
                                   (__attribute__((address_space(3))) void*)l, 16, 0, 0);
}

__device__ __forceinline__ bf16x8 ds_read_b128_asm(unsigned addr) {
  bf16x8 r;
  asm volatile("ds_read_b128 %0, %1" : "=v"(r) : "v"(addr));
  return r;
}

// ---------------- transpose tile body 32x32 ----------
__device__ __forceinline__ void transpose_body(const float* __restrict__ in,
                                               __hip_bfloat16* __restrict__ out,
                                               int K, int N, int bx, int by,
                                               float (*tile)[33], int tid) {
  int n0 = bx * 32, k0 = by * 32;
  int tx = tid & 31, ty = tid >> 5;  // 256 threads: 32 x 8
#pragma unroll
  for (int i = 0; i < 4; ++i)
    tile[ty + 8 * i][tx] = in[(size_t)(k0 + ty + 8 * i) * N + n0 + tx];
  __syncthreads();
#pragma unroll
  for (int i = 0; i < 4; ++i)
    out[(size_t)(n0 + ty + 8 * i) * K + k0 + tx] = __float2bfloat16(tile[tx][ty + 8 * i]);
}

// ---------------- merged small prep: encWt, decWt, eW1 cast, gather, csum ----------
__global__ __launch_bounds__(256) void prep_k(
    const float* __restrict__ enc_W, __hip_bfloat16* __restrict__ encWt,
    const float* __restrict__ dec_W, __hip_bfloat16* __restrict__ decWt,
    const float* __restrict__ eW1, __hip_bfloat16* __restrict__ eW1b,
    const int* __restrict__ ids, const float* __restrict__ emb,
    __hip_bfloat16* __restrict__ Aenc,
    const float* __restrict__ c2s_W, float* __restrict__ csum) {
  __shared__ float tile[32][33];
  int bid = blockIdx.x;
  int tid = threadIdx.x;
  if (bid < 512) {                        // enc_W [512][1024] -> encWt [1024][512]
    transpose_body(enc_W, encWt, 512, 1024, bid % 32, bid / 32, tile, tid);
  } else if (bid < 1024) {                // dec_W [1024][512] -> decWt [512][1024]
    int b = bid - 512;
    transpose_body(dec_W, decWt, 1024, 512, b % 16, b / 16, tile, tid);
  } else if (bid < 1280) {                // eW1 cast f32->bf16 (262144 elems / 4)
    int i = (bid - 1024) * 256 + tid;
    float4 v = ((const float4*)eW1)[i];
    __hip_bfloat16* o = eW1b + i * 4;
    o[0] = __float2bfloat16(v.x); o[1] = __float2bfloat16(v.y);
    o[2] = __float2bfloat16(v.z); o[3] = __float2bfloat16(v.w);
  } else if (bid < 3328) {                // embedding gather+cast
    int i = (bid - 1280) * 256 + tid;
    int idx = i * 4;
    int row = idx >> 9, col = idx & 511;  // E = 512
    float4 v = *(const float4*)(emb + (size_t)ids[row] * 512 + col);
    __hip_bfloat16* o = Aenc + idx;
    o[0] = __float2bfloat16(v.x); o[1] = __float2bfloat16(v.y);
    o[2] = __float2bfloat16(v.z); o[3] = __float2bfloat16(v.w);
  } else {                                // csum of c2s_W (4 blocks)
    int h = (bid - 3328) * 256 + tid;
    float a = 0.f;
#pragma unroll 8
    for (int m = 0; m < 64; ++m) a += c2s_W[m * 1024 + h];
    csum[h] = a;
  }
}

// ---------------- fused: gif_scan(enc) + out_W transpose (64x64 tiles, nt write) ----
// bid<128: GIF scan enc. bid>=128: out_W [512][32000] -> outWt [32000][512].
// 64x64 tiles: 256B read segments, 128B write segments; nt write (read only at end).
__global__ __launch_bounds__(256) void gif_trans_k(
    const float* __restrict__ u, float* __restrict__ sp,
    const float* __restrict__ out_W, __hip_bfloat16* __restrict__ outWt) {
  __shared__ float tile[64][65];   // [n][k]
  int bid = blockIdx.x;
  int tid = threadIdx.x;
  if (bid >= 128) {
    int b = bid - 128;              // 4000 tiles: 500 n x 8 k
    int n0 = (b % 500) * 64, k0 = (b / 500) * 64;
    int kg = tid >> 4, nf = tid & 15;   // 16 k-rows per pass, 16 float4/row
#pragma unroll
    for (int i = 0; i < 4; ++i) {
      int kr = kg + 16 * i;
      float4 v = *(const float4*)(out_W + (size_t)(k0 + kr) * 32000 + n0 + nf * 4);
      tile[nf * 4 + 0][kr] = v.x;
      tile[nf * 4 + 1][kr] = v.y;
      tile[nf * 4 + 2][kr] = v.z;
      tile[nf * 4 + 3][kr] = v.w;
    }
    __syncthreads();
#pragma unroll
    for (int i = 0; i < 4; ++i) {
      int nr = kg + 16 * i;
      float4 v = *(const float4*)&tile[nr][nf * 4];
      __hip_bfloat16 o[4] = {__float2bfloat16(v.x), __float2bfloat16(v.y),
                             __float2bfloat16(v.z), __float2bfloat16(v.w)};
      __builtin_nontemporal_store(*(s16x4*)o,
          (s16x4*)(outWt + (size_t)(n0 + nr) * 512 + k0 + nf * 4));
    }
    return;
  }
  const int S = 2048, C = 1024;
  int chunk = bid >> 3;                       // 8 blocks per chunk
  int gc = (bid & 7) * 256 + tid;             // 0..2047
  int b = (gc >= C) ? 1 : 0, ch = gc - b * C; // B = 2
  size_t base = (size_t)b * S * C + ch;

  const int CH = 128;
  int s_begin = chunk * CH;
  int sw = (chunk == 0) ? 0 : s_begin - 96;
  int warm = s_begin - sw;            // 0 or 96
  int total = CH + warm;              // 128 or 224
  const float* up = u + base + (size_t)sw * C;

  float v = 0.f;
  float bufA[16], bufB[16];
#pragma unroll
  for (int i = 0; i < 16; ++i) bufA[i] = up[(size_t)i * C];
  for (int t = 0; t < total; t += 32) {
#pragma unroll
    for (int i = 0; i < 16; ++i) bufB[i] = up[(size_t)(t + 16 + i) * C];
#pragma unroll
    for (int i = 0; i < 16; ++i) {
      v = fmaf(0.9f, v, bufA[i]);
      float spk = gif_spike(v);
      v -= spk;
      if (t + i >= warm) sp[base + (size_t)(sw + t + i) * C] = spk;
    }
    if (t + 32 < total) {
#pragma unroll
      for (int i = 0; i < 16; ++i) bufA[i] = up[(size_t)(t + 32 + i) * C];
    }
#pragma unroll
    for (int i = 0; i < 16; ++i) {
      v = fmaf(0.9f, v, bufB[i]);
      float spk = gif_spike(v);
      v -= spk;
      if (t + 16 + i >= warm) sp[base + (size_t)(sw + t + 16 + i) * C] = spk;
    }
  }
}

// ---------------- 128x128 bf16 GEMM (enc/dec): 2-phase dbuf + counted vmcnt + swizzle
__global__ __launch_bounds__(256) void gemm128_k(
    const __hip_bfloat16* __restrict__ A, const __hip_bfloat16* __restrict__ Bt,
    const float* __restrict__ bias, float* __restrict__ C, int N, int K, int GM) {
  __shared__ __align__(16) char smem[65536];  // buf b: A at b*32768, B at +16384

  int nwg = gridDim.x;
  int bid = blockIdx.x;
  int q = nwg >> 3, r = nwg & 7, xcd = bid & 7, bix = bid >> 3;
  int wg = (xcd < r ? xcd * (q + 1) : r * (q + 1) + (xcd - r) * q) + bix;
  int bm = wg % GM, bn = wg / GM;

  int tid = threadIdx.x;
  int lane = tid & 63, w = tid >> 6;
  int wm = w >> 1, wn = w & 1;

  const __hip_bfloat16* gA[4];
  const __hip_bfloat16* gB[4];
#pragma unroll
  for (int i = 0; i < 4; ++i) {
    int c = (w * 4 + i) * 64 + lane;
    int rr = c >> 3, sl = c & 7;
    int sg = sl ^ (rr & 7);
    gA[i] = A + (size_t)(bm * 128 + rr) * K + sg * 8;
    gB[i] = Bt + (size_t)(bn * 128 + rr) * K + sg * 8;
  }

  f32x4 acc[4][4];
#pragma unroll
  for (int i = 0; i < 4; ++i)
#pragma unroll
    for (int j = 0; j < 4; ++j) acc[i][j] = (f32x4){0.f, 0.f, 0.f, 0.f};

  auto stage = [&](int kt, int b) {
    int ko = kt * 64;
    char* baseA = smem + b * 32768;
    char* baseB = baseA + 16384;
#pragma unroll
    for (int i = 0; i < 4; ++i) {
      gload_lds16(gA[i] + ko, baseA + (w * 4 + i) * 1024);
      gload_lds16(gB[i] + ko, baseB + (w * 4 + i) * 1024);
    }
  };

  const int KT = K >> 6;
  stage(0, 0);
  asm volatile("s_waitcnt vmcnt(0)" ::: "memory");
  __builtin_amdgcn_s_barrier();
  int cur = 0;
  for (int kt = 0; kt < KT; ++kt) {
    if (kt + 1 < KT) {
      stage(kt + 1, cur ^ 1);
      asm volatile("s_waitcnt vmcnt(8)" ::: "memory");
    } else {
      asm volatile("s_waitcnt vmcnt(0)" ::: "memory");
    }
    __builtin_amdgcn_s_barrier();
    const char* smA = smem + cur * 32768;
    const char* smB = smA + 16384;
#pragma unroll
    for (int ks = 0; ks < 2; ++ks) {
      bf16x8 af[4], bfr[4];
#pragma unroll
      for (int f = 0; f < 4; ++f) {
        int R = wm * 64 + f * 16 + (lane & 15);
        int R2 = wn * 64 + f * 16 + (lane & 15);
        int sg = ks * 4 + (lane >> 4);
        af[f]  = *(const bf16x8*)(smA + R * 128 + ((sg ^ (R & 7)) << 4));
        bfr[f] = *(const bf16x8*)(smB + R2 * 128 + ((sg ^ (R2 & 7)) << 4));
      }
#pragma unroll
      for (int fm = 0; fm < 4; ++fm)
#pragma unroll
        for (int fn = 0; fn < 4; ++fn)
          acc[fm][fn] = __builtin_amdgcn_mfma_f32_16x16x32_bf16(af[fm], bfr[fn], acc[fm][fn], 0, 0, 0);
    }
    __builtin_amdgcn_sched_barrier(0);
    __builtin_amdgcn_s_barrier();
    cur ^= 1;
  }
  int rbase = bm * 128 + wm * 64 + ((lane >> 4) << 2);
  int cbase = bn * 128 + wn * 64 + (lane & 15);
#pragma unroll
  for (int fn = 0; fn < 4; ++fn) {
    int col = cbase + fn * 16;
    float bs = bias[col];
#pragma unroll
    for (int fm = 0; fm < 4; ++fm) {
      int row = rbase + fm * 16;
#pragma unroll
      for (int rr = 0; rr < 4; ++rr)
        C[(size_t)(row + rr) * N + col] = acc[fm][fn][rr] + bs;
    }
  }
}

// ---------------- 256x256 bf16 GEMM (out, M=4096 N=32000 K=512) — r16 version ------
// 8 waves, 128x64 wave tiles, 2 waves/SIMD. Whole-tile-ahead staging + vmcnt(8);
// within-wave lgkmcnt(12) split; LDS-transpose epilogue; NON-TEMPORAL C stores.
__global__ __launch_bounds__(512, 2) void gemm256_k(
    const __hip_bfloat16* __restrict__ A, const __hip_bfloat16* __restrict__ Bt,
    const float* __restrict__ bias, float* __restrict__ C, int N, int K) {
  __shared__ __align__(16) char smem[131072];  // buf b: A at b*65536 (32KB), B at +32768

  int nwg = gridDim.x;
  int bid = blockIdx.x;
  int q = nwg >> 3, r = nwg & 7, xcd = bid & 7, bix = bid >> 3;
  int wg = (xcd < r ? xcd * (q + 1) : r * (q + 1) + (xcd - r) * q) + bix;
  // supertile decode: stripe(8bm) -> group(5bn x 8bm, bm-fast)
  int S  = wg / 1000;         // 0..1
  int rr_ = wg - S * 1000;
  int g  = rr_ / 40;          // 0..24
  int t  = rr_ - g * 40;      // 0..39
  int bn = g * 5 + (t >> 3);  // 0..124
  int bm = S * 8 + (t & 7);   // 0..15

  int tid = threadIdx.x;
  int lane = tid & 63, w = tid >> 6;      // 8 waves
  int wm = w >> 2, wn = w & 3;            // 2 x 4 wave grid; wave tile 128x64

  int offA[4], offB[4];
#pragma unroll
  for (int i = 0; i < 4; ++i) {
    int c = (w * 4 + i) * 64 + lane;      // 0..2047
    int rw = c >> 3, sl = c & 7;
    int sg = sl ^ (rw & 7);               // pre-swizzled global k-slot
    offA[i] = (bm * 256 + rw) * K + sg * 8;
    offB[i] = rw * K + sg * 8;            // bn folded into base pointer
  }
  const __hip_bfloat16* Bb = Bt + (size_t)(bn * 256) * K;

  f32x4 acc[8][4];
#pragma unroll
  for (int i = 0; i < 8; ++i)
#pragma unroll
    for (int j = 0; j < 4; ++j) acc[i][j] = (f32x4){0.f, 0.f, 0.f, 0.f};

  auto stage = [&](int kt, int b) {
    int ko = kt * 64;
    char* baseA = smem + b * 65536;
    char* baseB = baseA + 32768;
#pragma unroll
    for (int i = 0; i < 4; ++i) {
      gload_lds16(A + offA[i] + ko, baseA + (w * 4 + i) * 1024);
      gload_lds16(Bb + offB[i] + ko, baseB + (w * 4 + i) * 1024);
    }
  };

  unsigned sbase = (unsigned)(uintptr_t)(lds_char_t*)smem;

  const int KT = K >> 6;
  stage(0, 0);
  int cur = 0;
  for (int kt = 0; kt < KT; ++kt) {
    if (kt + 1 < KT) {
      stage(kt + 1, cur ^ 1);                           // 8 loads in flight
      asm volatile("s_waitcnt vmcnt(8)" ::: "memory");  // wait only for tile kt's 8
    } else {
      asm volatile("s_waitcnt vmcnt(0)" ::: "memory");
    }
    __builtin_amdgcn_s_barrier();                        // LDS[cur] ready for all waves
    unsigned aA = sbase + cur * 65536;
    unsigned aB = aA + 32768;
    int sg0 = (lane >> 4);
    int sg1 = 4 + (lane >> 4);

    bf16x8 b0[4], b1[4], a0a[4], a0b[4], a1a[4], a1b[4];
    // ---- issue all 24 ds_reads (volatile: program order preserved) ----
#pragma unroll
    for (int f = 0; f < 4; ++f) {
      int R2 = wn * 64 + f * 16 + (lane & 15);
      b0[f] = ds_read_b128_asm(aB + R2 * 128 + ((sg0 ^ (R2 & 7)) << 4));
    }
#pragma unroll
    for (int f = 0; f < 4; ++f) {
      int R = wm * 128 + f * 16 + (lane & 15);
      a0a[f] = ds_read_b128_asm(aA + R * 128 + ((sg0 ^ (R & 7)) << 4));
    }
#pragma unroll
    for (int f = 0; f < 4; ++f) {
      int R = wm * 128 + (f + 4) * 16 + (lane & 15);
      a0b[f] = ds_read_b128_asm(aA + R * 128 + ((sg0 ^ (R & 7)) << 4));
    }
#pragma unroll
    for (int f = 0; f < 4; ++f) {
      int R2 = wn * 64 + f * 16 + (lane & 15);
      b1[f] = ds_read_b128_asm(aB + R2 * 128 + ((sg1 ^ (R2 & 7)) << 4));
    }
#pragma unroll
    for (int f = 0; f < 4; ++f) {
      int R = wm * 128 + f * 16 + (lane & 15);
      a1a[f] = ds_read_b128_asm(aA + R * 128 + ((sg1 ^ (R & 7)) << 4));
    }
#pragma unroll
    for (int f = 0; f < 4; ++f) {
      int R = wm * 128 + (f + 4) * 16 + (lane & 15);
      a1b[f] = ds_read_b128_asm(aA + R * 128 + ((sg1 ^ (R & 7)) << 4));
    }
    // ---- ks0 MFMA while ks1 reads drain ----
    asm volatile("s_waitcnt lgkmcnt(12)" ::: "memory");  // first 12 (ks0) complete
    __builtin_amdgcn_sched_barrier(0);
    __builtin_amdgcn_s_setprio(1);
#pragma unroll
    for (int fm = 0; fm < 4; ++fm)
#pragma unroll
      for (int fn = 0; fn < 4; ++fn)
        acc[fm][fn] = __builtin_amdgcn_mfma_f32_16x16x32_bf16(a0a[fm], b0[fn], acc[fm][fn], 0, 0, 0);
#pragma unroll
    for (int fm = 0; fm < 4; ++fm)
#pragma unroll
      for (int fn = 0; fn < 4; ++fn)
        acc[fm + 4][fn] = __builtin_amdgcn_mfma_f32_16x16x32_bf16(a0b[fm], b0[fn], acc[fm + 4][fn], 0, 0, 0);
    __builtin_amdgcn_s_setprio(0);
    // ---- ks1 MFMA ----
    asm volatile("s_waitcnt lgkmcnt(0)" ::: "memory");
    __builtin_amdgcn_sched_barrier(0);
    __builtin_amdgcn_s_setprio(1);
#pragma unroll
    for (int fm = 0; fm < 4; ++fm)
#pragma unroll
      for (int fn = 0; fn < 4; ++fn)
        acc[fm][fn] = __builtin_amdgcn_mfma_f32_16x16x32_bf16(a1a[fm], b1[fn], acc[fm][fn], 0, 0, 0);
#pragma unroll
    for (int fm = 0; fm < 4; ++fm)
#pragma unroll
      for (int fn = 0; fn < 4; ++fn)
        acc[fm + 4][fn] = __builtin_amdgcn_mfma_f32_16x16x32_bf16(a1b[fm], b1[fn], acc[fm + 4][fn], 0, 0, 0);
    __builtin_amdgcn_s_setprio(0);
    __builtin_amdgcn_sched_barrier(0);
    __builtin_amdgcn_s_barrier();                        // all waves done reading cur
    cur ^= 1;
  }

  // ---- epilogue: LDS-transpose -> contiguous NON-TEMPORAL dwordx4 stores ----
  float* sC = (float*)smem;
#pragma unroll
  for (int h = 0; h < 2; ++h) {
    __syncthreads();            // smem free (main loop done / prev half read done)
    if (wm == h) {
#pragma unroll
      for (int fn = 0; fn < 4; ++fn) {
        int lc = wn * 64 + fn * 16 + (lane & 15);
        float bs = bias[bn * 256 + lc];
#pragma unroll
        for (int fm = 0; fm < 8; ++fm)
#pragma unroll
          for (int rw = 0; rw < 4; ++rw) {
            int lr = fm * 16 + ((lane >> 4) << 2) + rw;  // 0..127 local row
            sC[lr * 256 + lc] = acc[fm][fn][rw] + bs;
          }
      }
    }
    __syncthreads();
    // 512 threads stream 128 rows x 1KB contiguous, nt (no L2 allocation)
#pragma unroll
    for (int it = 0; it < 16; ++it) {
      int lr = it * 8 + w;
      int lc = (tid & 63) * 4;
      f32x4 v = *(f32x4*)&sC[lr * 256 + lc];
      __builtin_nontemporal_store(v, (f32x4*)(C + (size_t)(bm * 256 + h * 128 + lr) * N + bn * 256 + lc));
    }
  }
}

// ---------------- GIF scan (dec), chunk-parallel, 64-thread blocks ----------------
__global__ void gif_scan_k(const float* __restrict__ u, __hip_bfloat16* __restrict__ out,
                           int S, int C, int bpc) {
  int chunk = blockIdx.x / bpc;
  int gc = (blockIdx.x - chunk * bpc) * 64 + threadIdx.x;
  int b = (gc >= C) ? 1 : 0, ch = gc - b * C;  // B = 2
  size_t base = (size_t)b * S * C + ch;

  const int CH = 128;
  int s_begin = chunk * CH;
  int sw = (chunk == 0) ? 0 : s_begin - 96;
  int warm = s_begin - sw;
  int total = CH + warm;
  const float* up = u + base + (size_t)sw * C;

  float v = 0.f;
  float bufA[16], bufB[16];
#pragma unroll
  for (int i = 0; i < 16; ++i) bufA[i] = up[(size_t)i * C];
  for (int t = 0; t < total; t += 32) {
#pragma unroll
    for (int i = 0; i < 16; ++i) bufB[i] = up[(size_t)(t + 16 + i) * C];
#pragma unroll
    for (int i = 0; i < 16; ++i) {
      v = fmaf(0.9f, v, bufA[i]);
      float spk = gif_spike(v);
      v -= spk;
      if (t + i >= warm) out[base + (size_t)(sw + t + i) * C] = __float2bfloat16(spk);
    }
    if (t + 32 < total) {
#pragma unroll
      for (int i = 0; i < 16; ++i) bufA[i] = up[(size_t)(t + 32 + i) * C];
    }
#pragma unroll
    for (int i = 0; i < 16; ++i) {
      v = fmaf(0.9f, v, bufB[i]);
      float spk = gif_spike(v);
      v -= spk;
      if (t + 16 + i >= warm) out[base + (size_t)(sw + t + 16 + i) * C] = __float2bfloat16(spk);
    }
  }
}

// ---------------- s2c: cont[4096,64] = sp[4096,1024] @ W[1024,64] + b ----------------
__global__ void s2c_k(const float* __restrict__ sp, const float* __restrict__ W,
                      const float* __restrict__ b, float* __restrict__ cont) {
  int n = threadIdx.x & 63, tg = threadIdx.x >> 6;
  int tok0 = blockIdx.x * 16 + tg * 4;
  const float* s0 = sp + (size_t)tok0 * 1024;
  float a0 = 0, a1 = 0, a2 = 0, a3 = 0;
#pragma unroll 8
  for (int k = 0; k < 1024; ++k) {
    float w = W[k * 64 + n];
    a0 += s0[k] * w;
    a1 += s0[k + 1024] * w;
    a2 += s0[k + 2048] * w;
    a3 += s0[k + 3072] * w;
  }
  float bb = b[n];
  cont[(size_t)(tok0 + 0) * 64 + n] = a0 + bb;
  cont[(size_t)(tok0 + 1) * 64 + n] = a1 + bb;
  cont[(size_t)(tok0 + 2) * 64 + n] = a2 + bb;
  cont[(size_t)(tok0 + 3) * 64 + n] = a3 + bb;
}

// ---------------- fused router + experts + y + rate (16 tokens/block, 8 waves) ------
__global__ __launch_bounds__(512) void moe_k(
    const float* __restrict__ cont,
    const float* __restrict__ rW1, const float* __restrict__ rb1,
    const float* __restrict__ rW2, const float* __restrict__ rb2,
    const __hip_bfloat16* __restrict__ eW1b, const float* __restrict__ eb1,
    const float* __restrict__ eW2, const float* __restrict__ eb2,
    const float* __restrict__ csum, const float* __restrict__ c2sb,
    __hip_bfloat16* __restrict__ rate) {
  __shared__ float sc[16][65];
  __shared__ float sh1[16][65];
  __shared__ float sgl[16][8];
  __shared__ float seo[16][8];
  __shared__ float sy[16];
  int tid = threadIdx.x;
  int t0 = blockIdx.x * 16;

  for (int i = tid; i < 1024; i += 512) sc[i >> 6][i & 63] = cont[(size_t)t0 * 64 + i];
  __syncthreads();

  // router layer 1: h1 = tanh(cont @ rW1 + rb1)   (16 tok x 64 units; threads 0..255)
  if (tid < 256) {
    int tok = tid >> 4, u0 = tid & 15;
#pragma unroll
    for (int uu = 0; uu < 4; ++uu) {
      int un = u0 + 16 * uu;
      float a = rb1[un];
#pragma unroll 8
      for (int m = 0; m < 64; ++m) a += sc[tok][m] * rW1[m * 64 + un];
      sh1[tok][un] = ftanh(a);
    }
  }
  __syncthreads();
  // router layer 2: gl = h1 @ rW2 + rb2  (16 tok x 8 experts)
  if (tid < 128) {
    int tok = tid >> 3, e = tid & 7;
    float a = rb2[e];
#pragma unroll 8
    for (int j = 0; j < 64; ++j) a += sh1[tok][j] * rW2[j * 8 + e];
    sgl[tok][e] = a;
  }
  __syncthreads();

  // experts (dense, all 8): wave w owns expert w, all 16 tokens (eW1 in bf16)
  {
    int jj = tid & 63, e = tid >> 6;
    float eop[16];
#pragma unroll
    for (int t = 0; t < 16; ++t) eop[t] = 0.f;
#pragma unroll
    for (int jr = 0; jr < 2; ++jr) {
      int j = jj * 4 + jr * 256;
      float4 bb = *(const float4*)(eb1 + e * 512 + j);
      float4 a[16];
#pragma unroll
      for (int t = 0; t < 16; ++t) a[t] = bb;
      const ushort4* wp = (const ushort4*)(eW1b + (size_t)e * 64 * 512 + j);
#pragma unroll 4
      for (int m = 0; m < 64; ++m) {
        ushort4 wu = wp[(size_t)m * 128];
        float wx = b2f(wu.x), wy = b2f(wu.y), wz = b2f(wu.z), ww = b2f(wu.w);
#pragma unroll
        for (int t = 0; t < 16; ++t) {
          float c = sc[t][m];
          a[t].x += wx * c; a[t].y += wy * c;
          a[t].z += wz * c; a[t].w += ww * c;
        }
      }
      float4 w2 = *(const float4*)(eW2 + e * 512 + j);
#pragma unroll
      for (int t = 0; t < 16; ++t)
        eop[t] += ftanh(a[t].x) * w2.x + ftanh(a[t].y) * w2.y +
                  ftanh(a[t].z) * w2.z + ftanh(a[t].w) * w2.w;
    }
#pragma unroll
    for (int t = 0; t < 16; ++t) {
#pragma unroll
      for (int off = 32; off > 0; off >>= 1) eop[t] += __shfl_down(eop[t], off);
    }
    if (jj == 0) {
      float b2 = eb2[e];
#pragma unroll
      for (int t = 0; t < 16; ++t) seo[t][e] = eop[t] + b2;
    }
  }
  __syncthreads();

  // softmax + top-2 + y (one thread per token)
  if (tid < 16) {
    int tok = tid;
    float mx = sgl[tok][0];
#pragma unroll
    for (int e = 1; e < 8; ++e) mx = fmaxf(mx, sgl[tok][e]);
#pragma unroll
    for (int e = 0; e < 8; ++e) sgl[tok][e] = __expf(sgl[tok][e] - mx);  // overwrite with exp
    int i0 = 0;
#pragma unroll
    for (int e = 1; e < 8; ++e) if (sgl[tok][e] > sgl[tok][i0]) i0 = e;
    int i1 = (i0 == 0) ? 1 : 0;
#pragma unroll
    for (int e = 0; e < 8; ++e) if (e != i0 && sgl[tok][e] > sgl[tok][i1]) i1 = e;
    float g0 = sgl[tok][i0], g1 = sgl[tok][i1];
    sy[tok] = (g0 * seo[tok][i0] + g1 * seo[tok][i1]) / (g0 + g1);
  }
  __syncthreads();

  // rate = sigmoid(y * csum + c2s_b)  -> bf16 [16 tok x 1024]
  for (int i = tid; i < 16 * 1024; i += 512) {
    int tok = i >> 10, h = i & 1023;
    float r = fsig(sy[tok] * csum[h] + c2sb[h]);
    rate[(size_t)(t0 + tok) * 1024 + h] = __float2bfloat16(r);
  }
}

// ---------------- launch ----------------
extern "C" void kernel_launch(void* const* d_in, const int* in_sizes, int n_in,
                              void* d_out, int out_size, void* d_ws, size_t ws_size,
                              hipStream_t stream) {
  (void)in_sizes; (void)n_in; (void)out_size; (void)ws_size;
  const int*   ids   = (const int*)d_in[0];
  const float* emb   = (const float*)d_in[1];
  const float* enc_W = (const float*)d_in[2];
  const float* enc_b = (const float*)d_in[3];
  const float* s2c_W = (const float*)d_in[4];
  const float* s2c_b = (const float*)d_in[5];
  const float* rW1   = (const float*)d_in[6];
  const float* rb1   = (const float*)d_in[7];
  const float* rW2   = (const float*)d_in[8];
  const float* rb2   = (const float*)d_in[9];
  const float* eW1   = (const float*)d_in[10];
  const float* eb1   = (const float*)d_in[11];
  const float* eW2   = (const float*)d_in[12];
  const float* eb2   = (const float*)d_in[13];
  const float* c2s_W = (const float*)d_in[14];
  const float* c2s_b = (const float*)d_in[15];
  const float* dec_W = (const float*)d_in[16];
  const float* dec_b = (const float*)d_in[17];
  const float* out_W = (const float*)d_in[18];
  const float* out_b = (const float*)d_in[19];
  float* out = (float*)d_out;

  char* ws = (char*)d_ws;
  size_t off = 0;
  auto alloc = [&](size_t bytes) -> char* {
    off = (off + 255) & ~(size_t)255;
    char* p = ws + off;
    off += bytes;
    return p;
  };
  __hip_bfloat16* outWt = (__hip_bfloat16*)alloc(32000ull * 512 * 2);
  __hip_bfloat16* encWt = (__hip_bfloat16*)alloc(1024ull * 512 * 2);
  __hip_bfloat16* decWt = (__hip_bfloat16*)alloc(512ull * 1024 * 2);
  __hip_bfloat16* eW1b  = (__hip_bfloat16*)alloc(8ull * 64 * 512 * 2);
  __hip_bfloat16* Aenc  = (__hip_bfloat16*)alloc(4096ull * 512 * 2);
  float* u_enc  = (float*)alloc(4096ull * 1024 * 4);
  float* sp_enc = (float*)alloc(4096ull * 1024 * 4);
  float* cont   = (float*)alloc(4096ull * 64 * 4);
  float* csum   = (float*)alloc(1024 * 4);
  float* u_dec  = (float*)alloc(4096ull * 512 * 4);
  __hip_bfloat16* dec = (__hip_bfloat16*)alloc(4096ull * 512 * 2);
  __hip_bfloat16* rate = (__hip_bfloat16*)u_enc;  // reuse: u_enc dead after gif

  // small prep: encWt, decWt, eW1b, gather, csum (3332 blocks)
  prep_k<<<3332, 256, 0, stream>>>(enc_W, encWt, dec_W, decWt,
                                   eW1, eW1b, ids, emb, Aenc, c2s_W, csum);

  // pipeline (out_W transpose fused into gif_enc launch — independent work)
  gemm128_k<<<32 * 8, 256, 0, stream>>>(Aenc, encWt, enc_b, u_enc, 1024, 512, 32);
  gif_trans_k<<<128 + 4000, 256, 0, stream>>>(u_enc, sp_enc, out_W, outWt);
  s2c_k<<<256, 256, 0, stream>>>(sp_enc, s2c_W, s2c_b, cont);
  moe_k<<<256, 512, 0, stream>>>(cont, rW1, rb1, rW2, rb2, eW1b, eb1, eW2, eb2, csum, c2s_b, rate);
  gemm128_k<<<32 * 4, 256, 0, stream>>>(rate, decWt, dec_b, u_dec, 512, 1024, 32);
  gif_scan_k<<<16 * 16, 64, 0, stream>>>(u_dec, dec, 2048, 512, 16);
  gemm256_k<<<2000, 512, 0, stream>>>(dec, outWt, out_b, out, 32000, 512);
}

// Round 18
// 376.681 us; speedup vs baseline: 1.0571x; 1.0571x over previous
//
#include <hip/hip_runtime.h>
#include <hip/hip_bf16.h>
#include <stdint.h>

typedef __attribute__((ext_vector_type(8))) short bf16x8;
typedef __attribute__((ext_vector_type(4))) float f32x4;
typedef __attribute__((address_space(3))) char lds_char_t;

#define LOG2E_X2 2.885390081777927f
#define GIF_A 5.770780163555854f  // 4*log2(e)

__device__ __forceinline__ float fexp2(float x) { return __builtin_amdgcn_exp2f(x); }
__device__ __forceinline__ float frcp(float x)  { return __builtin_amdgcn_rcpf(x); }
__device__ __forceinline__ float gif_spike(float v) {
  return frcp(1.f + fexp2(fmaf(v, -GIF_A, GIF_A)));
}
__device__ __forceinline__ float fsig(float x)  { return frcp(1.f + fexp2(-1.442695040888963f * x)); }
__device__ __forceinline__ float ftanh(float x) { return 1.f - 2.f * frcp(1.f + fexp2(LOG2E_X2 * x)); }
__device__ __forceinline__ float b2f(unsigned short u) {
  return __uint_as_float((unsigned)u << 16);
}

__device__ __forceinline__ void gload_lds16(const void* g, void* l) {
  __builtin_amdgcn_global_load_lds((__attribute__((address_space(1))) void*)(uintptr_t)g,
                                   (__attribute__((address_space(3))) void*)l, 16, 0, 0);
}

__device__ __forceinline__ bf16x8 ds_read_b128_asm(unsigned addr) {
  bf16x8 r;
  asm volatile("ds_read_b128 %0, %1" : "=v"(r) : "v"(addr));
  return r;
}

// ---------------- transpose tile body 32x32 ----------
__device__ __forceinline__ void transpose_body(const float* __restrict__ in,
                                               __hip_bfloat16* __restrict__ out,
                                               int K, int N, int bx, int by,
                                               float (*tile)[33], int tid) {
  int n0 = bx * 32, k0 = by * 32;
  int tx = tid & 31, ty = tid >> 5;  // 256 threads: 32 x 8
#pragma unroll
  for (int i = 0; i < 4; ++i)
    tile[ty + 8 * i][tx] = in[(size_t)(k0 + ty + 8 * i) * N + n0 + tx];
  __syncthreads();
#pragma unroll
  for (int i = 0; i < 4; ++i)
    out[(size_t)(n0 + ty + 8 * i) * K + k0 + tx] = __float2bfloat16(tile[tx][ty + 8 * i]);
}

// ---------------- merged small prep: encWt, decWt, eW1 cast, gather, csum ----------
__global__ __launch_bounds__(256) void prep_k(
    const float* __restrict__ enc_W, __hip_bfloat16* __restrict__ encWt,
    const float* __restrict__ dec_W, __hip_bfloat16* __restrict__ decWt,
    const float* __restrict__ eW1, __hip_bfloat16* __restrict__ eW1b,
    const int* __restrict__ ids, const float* __restrict__ emb,
    __hip_bfloat16* __restrict__ Aenc,
    const float* __restrict__ c2s_W, float* __restrict__ csum) {
  __shared__ float tile[32][33];
  int bid = blockIdx.x;
  int tid = threadIdx.x;
  if (bid < 512) {                        // enc_W [512][1024] -> encWt [1024][512]
    transpose_body(enc_W, encWt, 512, 1024, bid % 32, bid / 32, tile, tid);
  } else if (bid < 1024) {                // dec_W [1024][512] -> decWt [512][1024]
    int b = bid - 512;
    transpose_body(dec_W, decWt, 1024, 512, b % 16, b / 16, tile, tid);
  } else if (bid < 1280) {                // eW1 cast f32->bf16 (262144 elems / 4)
    int i = (bid - 1024) * 256 + tid;
    float4 v = ((const float4*)eW1)[i];
    __hip_bfloat16* o = eW1b + i * 4;
    o[0] = __float2bfloat16(v.x); o[1] = __float2bfloat16(v.y);
    o[2] = __float2bfloat16(v.z); o[3] = __float2bfloat16(v.w);
  } else if (bid < 3328) {                // embedding gather+cast
    int i = (bid - 1280) * 256 + tid;
    int idx = i * 4;
    int row = idx >> 9, col = idx & 511;  // E = 512
    float4 v = *(const float4*)(emb + (size_t)ids[row] * 512 + col);
    __hip_bfloat16* o = Aenc + idx;
    o[0] = __float2bfloat16(v.x); o[1] = __float2bfloat16(v.y);
    o[2] = __float2bfloat16(v.z); o[3] = __float2bfloat16(v.w);
  } else {                                // csum of c2s_W (4 blocks)
    int h = (bid - 3328) * 256 + tid;
    float a = 0.f;
#pragma unroll 8
    for (int m = 0; m < 64; ++m) a += c2s_W[m * 1024 + h];
    csum[h] = a;
  }
}

// ---------------- fused: gif_scan(enc) + out_W transpose (32x32 tiles, r16) --------
__global__ __launch_bounds__(256) void gif_trans_k(
    const float* __restrict__ u, float* __restrict__ sp,
    const float* __restrict__ out_W, __hip_bfloat16* __restrict__ outWt) {
  __shared__ float tile[32][33];
  int bid = blockIdx.x;
  int tid = threadIdx.x;
  if (bid >= 128) {
    int b = bid - 128;
    transpose_body(out_W, outWt, 512, 32000, b % 1000, b / 1000, tile, tid);
    return;
  }
  const int S = 2048, C = 1024;
  int chunk = bid >> 3;                       // 8 blocks per chunk
  int gc = (bid & 7) * 256 + tid;             // 0..2047
  int b = (gc >= C) ? 1 : 0, ch = gc - b * C; // B = 2
  size_t base = (size_t)b * S * C + ch;

  const int CH = 128;
  int s_begin = chunk * CH;
  int sw = (chunk == 0) ? 0 : s_begin - 96;
  int warm = s_begin - sw;            // 0 or 96
  int total = CH + warm;              // 128 or 224
  const float* up = u + base + (size_t)sw * C;

  float v = 0.f;
  float bufA[16], bufB[16];
#pragma unroll
  for (int i = 0; i < 16; ++i) bufA[i] = up[(size_t)i * C];
  for (int t = 0; t < total; t += 32) {
#pragma unroll
    for (int i = 0; i < 16; ++i) bufB[i] = up[(size_t)(t + 16 + i) * C];
#pragma unroll
    for (int i = 0; i < 16; ++i) {
      v = fmaf(0.9f, v, bufA[i]);
      float spk = gif_spike(v);
      v -= spk;
      if (t + i >= warm)
        __builtin_nontemporal_store(spk, &sp[base + (size_t)(sw + t + i) * C]);
    }
    if (t + 32 < total) {
#pragma unroll
      for (int i = 0; i < 16; ++i) bufA[i] = up[(size_t)(t + 32 + i) * C];
    }
#pragma unroll
    for (int i = 0; i < 16; ++i) {
      v = fmaf(0.9f, v, bufB[i]);
      float spk = gif_spike(v);
      v -= spk;
      if (t + 16 + i >= warm)
        __builtin_nontemporal_store(spk, &sp[base + (size_t)(sw + t + 16 + i) * C]);
    }
  }
}

// ---------------- 128x128 bf16 GEMM (enc/dec): 2-phase dbuf + counted vmcnt + swizzle
// NEW: LDS-transpose epilogue (128x128 f32 = 64KB = smem) + contiguous nt stores.
__global__ __launch_bounds__(256) void gemm128_k(
    const __hip_bfloat16* __restrict__ A, const __hip_bfloat16* __restrict__ Bt,
    const float* __restrict__ bias, float* __restrict__ C, int N, int K, int GM) {
  __shared__ __align__(16) char smem[65536];  // buf b: A at b*32768, B at +16384

  int nwg = gridDim.x;
  int bid = blockIdx.x;
  int q = nwg >> 3, r = nwg & 7, xcd = bid & 7, bix = bid >> 3;
  int wg = (xcd < r ? xcd * (q + 1) : r * (q + 1) + (xcd - r) * q) + bix;
  int bm = wg % GM, bn = wg / GM;

  int tid = threadIdx.x;
  int lane = tid & 63, w = tid >> 6;
  int wm = w >> 1, wn = w & 1;

  const __hip_bfloat16* gA[4];
  const __hip_bfloat16* gB[4];
#pragma unroll
  for (int i = 0; i < 4; ++i) {
    int c = (w * 4 + i) * 64 + lane;
    int rr = c >> 3, sl = c & 7;
    int sg = sl ^ (rr & 7);
    gA[i] = A + (size_t)(bm * 128 + rr) * K + sg * 8;
    gB[i] = Bt + (size_t)(bn * 128 + rr) * K + sg * 8;
  }

  f32x4 acc[4][4];
#pragma unroll
  for (int i = 0; i < 4; ++i)
#pragma unroll
    for (int j = 0; j < 4; ++j) acc[i][j] = (f32x4){0.f, 0.f, 0.f, 0.f};

  auto stage = [&](int kt, int b) {
    int ko = kt * 64;
    char* baseA = smem + b * 32768;
    char* baseB = baseA + 16384;
#pragma unroll
    for (int i = 0; i < 4; ++i) {
      gload_lds16(gA[i] + ko, baseA + (w * 4 + i) * 1024);
      gload_lds16(gB[i] + ko, baseB + (w * 4 + i) * 1024);
    }
  };

  const int KT = K >> 6;
  stage(0, 0);
  asm volatile("s_waitcnt vmcnt(0)" ::: "memory");
  __builtin_amdgcn_s_barrier();
  int cur = 0;
  for (int kt = 0; kt < KT; ++kt) {
    if (kt + 1 < KT) {
      stage(kt + 1, cur ^ 1);
      asm volatile("s_waitcnt vmcnt(8)" ::: "memory");
    } else {
      asm volatile("s_waitcnt vmcnt(0)" ::: "memory");
    }
    __builtin_amdgcn_s_barrier();
    const char* smA = smem + cur * 32768;
    const char* smB = smA + 16384;
#pragma unroll
    for (int ks = 0; ks < 2; ++ks) {
      bf16x8 af[4], bfr[4];
#pragma unroll
      for (int f = 0; f < 4; ++f) {
        int R = wm * 64 + f * 16 + (lane & 15);
        int R2 = wn * 64 + f * 16 + (lane & 15);
        int sg = ks * 4 + (lane >> 4);
        af[f]  = *(const bf16x8*)(smA + R * 128 + ((sg ^ (R & 7)) << 4));
        bfr[f] = *(const bf16x8*)(smB + R2 * 128 + ((sg ^ (R2 & 7)) << 4));
      }
#pragma unroll
      for (int fm = 0; fm < 4; ++fm)
#pragma unroll
        for (int fn = 0; fn < 4; ++fn)
          acc[fm][fn] = __builtin_amdgcn_mfma_f32_16x16x32_bf16(af[fm], bfr[fn], acc[fm][fn], 0, 0, 0);
    }
    __builtin_amdgcn_sched_barrier(0);
    __builtin_amdgcn_s_barrier();
    cur ^= 1;
  }

  // ---- epilogue: LDS-transpose (128x128 f32 fills all 64KB) -> contiguous nt stores
  float* sC = (float*)smem;
  __syncthreads();
#pragma unroll
  for (int fn = 0; fn < 4; ++fn) {
    int lc = wn * 64 + fn * 16 + (lane & 15);
    float bs = bias[bn * 128 + lc];
#pragma unroll
    for (int fm = 0; fm < 4; ++fm)
#pragma unroll
      for (int rw = 0; rw < 4; ++rw) {
        int lr = wm * 64 + fm * 16 + ((lane >> 4) << 2) + rw;
        sC[lr * 128 + lc] = acc[fm][fn][rw] + bs;
      }
  }
  __syncthreads();
  // 256 threads stream 128 rows x 512B contiguous
#pragma unroll
  for (int it = 0; it < 16; ++it) {
    int lr = it * 8 + (tid >> 5);
    int lc = (tid & 31) * 4;
    f32x4 v = *(f32x4*)&sC[lr * 128 + lc];
    __builtin_nontemporal_store(v, (f32x4*)(C + (size_t)(bm * 128 + lr) * N + bn * 128 + lc));
  }
}

// ---------------- 256x256 bf16 GEMM (out, M=4096 N=32000 K=512) — r16 version ------
__global__ __launch_bounds__(512, 2) void gemm256_k(
    const __hip_bfloat16* __restrict__ A, const __hip_bfloat16* __restrict__ Bt,
    const float* __restrict__ bias, float* __restrict__ C, int N, int K) {
  __shared__ __align__(16) char smem[131072];  // buf b: A at b*65536 (32KB), B at +32768

  int nwg = gridDim.x;
  int bid = blockIdx.x;
  int q = nwg >> 3, r = nwg & 7, xcd = bid & 7, bix = bid >> 3;
  int wg = (xcd < r ? xcd * (q + 1) : r * (q + 1) + (xcd - r) * q) + bix;
  // supertile decode: stripe(8bm) -> group(5bn x 8bm, bm-fast)
  int S  = wg / 1000;         // 0..1
  int rr_ = wg - S * 1000;
  int g  = rr_ / 40;          // 0..24
  int t  = rr_ - g * 40;      // 0..39
  int bn = g * 5 + (t >> 3);  // 0..124
  int bm = S * 8 + (t & 7);   // 0..15

  int tid = threadIdx.x;
  int lane = tid & 63, w = tid >> 6;      // 8 waves
  int wm = w >> 2, wn = w & 3;            // 2 x 4 wave grid; wave tile 128x64

  int offA[4], offB[4];
#pragma unroll
  for (int i = 0; i < 4; ++i) {
    int c = (w * 4 + i) * 64 + lane;      // 0..2047
    int rw = c >> 3, sl = c & 7;
    int sg = sl ^ (rw & 7);               // pre-swizzled global k-slot
    offA[i] = (bm * 256 + rw) * K + sg * 8;
    offB[i] = rw * K + sg * 8;            // bn folded into base pointer
  }
  const __hip_bfloat16* Bb = Bt + (size_t)(bn * 256) * K;

  f32x4 acc[8][4];
#pragma unroll
  for (int i = 0; i < 8; ++i)
#pragma unroll
    for (int j = 0; j < 4; ++j) acc[i][j] = (f32x4){0.f, 0.f, 0.f, 0.f};

  auto stage = [&](int kt, int b) {
    int ko = kt * 64;
    char* baseA = smem + b * 65536;
    char* baseB = baseA + 32768;
#pragma unroll
    for (int i = 0; i < 4; ++i) {
      gload_lds16(A + offA[i] + ko, baseA + (w * 4 + i) * 1024);
      gload_lds16(Bb + offB[i] + ko, baseB + (w * 4 + i) * 1024);
    }
  };

  unsigned sbase = (unsigned)(uintptr_t)(lds_char_t*)smem;

  const int KT = K >> 6;
  stage(0, 0);
  int cur = 0;
  for (int kt = 0; kt < KT; ++kt) {
    if (kt + 1 < KT) {
      stage(kt + 1, cur ^ 1);                           // 8 loads in flight
      asm volatile("s_waitcnt vmcnt(8)" ::: "memory");  // wait only for tile kt's 8
    } else {
      asm volatile("s_waitcnt vmcnt(0)" ::: "memory");
    }
    __builtin_amdgcn_s_barrier();                        // LDS[cur] ready for all waves
    unsigned aA = sbase + cur * 65536;
    unsigned aB = aA + 32768;
    int sg0 = (lane >> 4);
    int sg1 = 4 + (lane >> 4);

    bf16x8 b0[4], b1[4], a0a[4], a0b[4], a1a[4], a1b[4];
    // ---- issue all 24 ds_reads (volatile: program order preserved) ----
#pragma unroll
    for (int f = 0; f < 4; ++f) {
      int R2 = wn * 64 + f * 16 + (lane & 15);
      b0[f] = ds_read_b128_asm(aB + R2 * 128 + ((sg0 ^ (R2 & 7)) << 4));
    }
#pragma unroll
    for (int f = 0; f < 4; ++f) {
      int R = wm * 128 + f * 16 + (lane & 15);
      a0a[f] = ds_read_b128_asm(aA + R * 128 + ((sg0 ^ (R & 7)) << 4));
    }
#pragma unroll
    for (int f = 0; f < 4; ++f) {
      int R = wm * 128 + (f + 4) * 16 + (lane & 15);
      a0b[f] = ds_read_b128_asm(aA + R * 128 + ((sg0 ^ (R & 7)) << 4));
    }
#pragma unroll
    for (int f = 0; f < 4; ++f) {
      int R2 = wn * 64 + f * 16 + (lane & 15);
      b1[f] = ds_read_b128_asm(aB + R2 * 128 + ((sg1 ^ (R2 & 7)) << 4));
    }
#pragma unroll
    for (int f = 0; f < 4; ++f) {
      int R = wm * 128 + f * 16 + (lane & 15);
      a1a[f] = ds_read_b128_asm(aA + R * 128 + ((sg1 ^ (R & 7)) << 4));
    }
#pragma unroll
    for (int f = 0; f < 4; ++f) {
      int R = wm * 128 + (f + 4) * 16 + (lane & 15);
      a1b[f] = ds_read_b128_asm(aA + R * 128 + ((sg1 ^ (R & 7)) << 4));
    }
    // ---- ks0 MFMA while ks1 reads drain ----
    asm volatile("s_waitcnt lgkmcnt(12)" ::: "memory");  // first 12 (ks0) complete
    __builtin_amdgcn_sched_barrier(0);
    __builtin_amdgcn_s_setprio(1);
#pragma unroll
    for (int fm = 0; fm < 4; ++fm)
#pragma unroll
      for (int fn = 0; fn < 4; ++fn)
        acc[fm][fn] = __builtin_amdgcn_mfma_f32_16x16x32_bf16(a0a[fm], b0[fn], acc[fm][fn], 0, 0, 0);
#pragma unroll
    for (int fm = 0; fm < 4; ++fm)
#pragma unroll
      for (int fn = 0; fn < 4; ++fn)
        acc[fm + 4][fn] = __builtin_amdgcn_mfma_f32_16x16x32_bf16(a0b[fm], b0[fn], acc[fm + 4][fn], 0, 0, 0);
    __builtin_amdgcn_s_setprio(0);
    // ---- ks1 MFMA ----
    asm volatile("s_waitcnt lgkmcnt(0)" ::: "memory");
    __builtin_amdgcn_sched_barrier(0);
    __builtin_amdgcn_s_setprio(1);
#pragma unroll
    for (int fm = 0; fm < 4; ++fm)
#pragma unroll
      for (int fn = 0; fn < 4; ++fn)
        acc[fm][fn] = __builtin_amdgcn_mfma_f32_16x16x32_bf16(a1a[fm], b1[fn], acc[fm][fn], 0, 0, 0);
#pragma unroll
    for (int fm = 0; fm < 4; ++fm)
#pragma unroll
      for (int fn = 0; fn < 4; ++fn)
        acc[fm + 4][fn] = __builtin_amdgcn_mfma_f32_16x16x32_bf16(a1b[fm], b1[fn], acc[fm + 4][fn], 0, 0, 0);
    __builtin_amdgcn_s_setprio(0);
    __builtin_amdgcn_sched_barrier(0);
    __builtin_amdgcn_s_barrier();                        // all waves done reading cur
    cur ^= 1;
  }

  // ---- epilogue: LDS-transpose -> contiguous NON-TEMPORAL dwordx4 stores ----
  float* sC = (float*)smem;
#pragma unroll
  for (int h = 0; h < 2; ++h) {
    __syncthreads();            // smem free (main loop done / prev half read done)
    if (wm == h) {
#pragma unroll
      for (int fn = 0; fn < 4; ++fn) {
        int lc = wn * 64 + fn * 16 + (lane & 15);
        float bs = bias[bn * 256 + lc];
#pragma unroll
        for (int fm = 0; fm < 8; ++fm)
#pragma unroll
          for (int rw = 0; rw < 4; ++rw) {
            int lr = fm * 16 + ((lane >> 4) << 2) + rw;  // 0..127 local row
            sC[lr * 256 + lc] = acc[fm][fn][rw] + bs;
          }
      }
    }
    __syncthreads();
    // 512 threads stream 128 rows x 1KB contiguous, nt (no L2 allocation)
#pragma unroll
    for (int it = 0; it < 16; ++it) {
      int lr = it * 8 + w;
      int lc = (tid & 63) * 4;
      f32x4 v = *(f32x4*)&sC[lr * 256 + lc];
      __builtin_nontemporal_store(v, (f32x4*)(C + (size_t)(bm * 256 + h * 128 + lr) * N + bn * 256 + lc));
    }
  }
}

// ---------------- GIF scan (dec), chunk-parallel, 64-thread blocks ----------------
__global__ void gif_scan_k(const float* __restrict__ u, __hip_bfloat16* __restrict__ out,
                           int S, int C, int bpc) {
  int chunk = blockIdx.x / bpc;
  int gc = (blockIdx.x - chunk * bpc) * 64 + threadIdx.x;
  int b = (gc >= C) ? 1 : 0, ch = gc - b * C;  // B = 2
  size_t base = (size_t)b * S * C + ch;

  const int CH = 128;
  int s_begin = chunk * CH;
  int sw = (chunk == 0) ? 0 : s_begin - 96;
  int warm = s_begin - sw;
  int total = CH + warm;
  const float* up = u + base + (size_t)sw * C;

  float v = 0.f;
  float bufA[16], bufB[16];
#pragma unroll
  for (int i = 0; i < 16; ++i) bufA[i] = up[(size_t)i * C];
  for (int t = 0; t < total; t += 32) {
#pragma unroll
    for (int i = 0; i < 16; ++i) bufB[i] = up[(size_t)(t + 16 + i) * C];
#pragma unroll
    for (int i = 0; i < 16; ++i) {
      v = fmaf(0.9f, v, bufA[i]);
      float spk = gif_spike(v);
      v -= spk;
      if (t + i >= warm) {
        __hip_bfloat16 hb = __float2bfloat16(spk);
        __builtin_nontemporal_store(*(short*)&hb, (short*)&out[base + (size_t)(sw + t + i) * C]);
      }
    }
    if (t + 32 < total) {
#pragma unroll
      for (int i = 0; i < 16; ++i) bufA[i] = up[(size_t)(t + 32 + i) * C];
    }
#pragma unroll
    for (int i = 0; i < 16; ++i) {
      v = fmaf(0.9f, v, bufB[i]);
      float spk = gif_spike(v);
      v -= spk;
      if (t + 16 + i >= warm) {
        __hip_bfloat16 hb = __float2bfloat16(spk);
        __builtin_nontemporal_store(*(short*)&hb, (short*)&out[base + (size_t)(sw + t + 16 + i) * C]);
      }
    }
  }
}

// ---------------- s2c: cont[4096,64] = sp[4096,1024] @ W[1024,64] + b ----------------
__global__ void s2c_k(const float* __restrict__ sp, const float* __restrict__ W,
                      const float* __restrict__ b, float* __restrict__ cont) {
  int n = threadIdx.x & 63, tg = threadIdx.x >> 6;
  int tok0 = blockIdx.x * 16 + tg * 4;
  const float* s0 = sp + (size_t)tok0 * 1024;
  float a0 = 0, a1 = 0, a2 = 0, a3 = 0;
#pragma unroll 8
  for (int k = 0; k < 1024; ++k) {
    float w = W[k * 64 + n];
    a0 += s0[k] * w;
    a1 += s0[k + 1024] * w;
    a2 += s0[k + 2048] * w;
    a3 += s0[k + 3072] * w;
  }
  float bb = b[n];
  cont[(size_t)(tok0 + 0) * 64 + n] = a0 + bb;
  cont[(size_t)(tok0 + 1) * 64 + n] = a1 + bb;
  cont[(size_t)(tok0 + 2) * 64 + n] = a2 + bb;
  cont[(size_t)(tok0 + 3) * 64 + n] = a3 + bb;
}

// ---------------- fused router + experts + y + rate (16 tokens/block, 8 waves) ------
__global__ __launch_bounds__(512) void moe_k(
    const float* __restrict__ cont,
    const float* __restrict__ rW1, const float* __restrict__ rb1,
    const float* __restrict__ rW2, const float* __restrict__ rb2,
    const __hip_bfloat16* __restrict__ eW1b, const float* __restrict__ eb1,
    const float* __restrict__ eW2, const float* __restrict__ eb2,
    const float* __restrict__ csum, const float* __restrict__ c2sb,
    __hip_bfloat16* __restrict__ rate) {
  __shared__ float sc[16][65];
  __shared__ float sh1[16][65];
  __shared__ float sgl[16][8];
  __shared__ float seo[16][8];
  __shared__ float sy[16];
  int tid = threadIdx.x;
  int t0 = blockIdx.x * 16;

  for (int i = tid; i < 1024; i += 512) sc[i >> 6][i & 63] = cont[(size_t)t0 * 64 + i];
  __syncthreads();

  // router layer 1: h1 = tanh(cont @ rW1 + rb1)   (16 tok x 64 units; threads 0..255)
  if (tid < 256) {
    int tok = tid >> 4, u0 = tid & 15;
#pragma unroll
    for (int uu = 0; uu < 4; ++uu) {
      int un = u0 + 16 * uu;
      float a = rb1[un];
#pragma unroll 8
      for (int m = 0; m < 64; ++m) a += sc[tok][m] * rW1[m * 64 + un];
      sh1[tok][un] = ftanh(a);
    }
  }
  __syncthreads();
  // router layer 2: gl = h1 @ rW2 + rb2  (16 tok x 8 experts)
  if (tid < 128) {
    int tok = tid >> 3, e = tid & 7;
    float a = rb2[e];
#pragma unroll 8
    for (int j = 0; j < 64; ++j) a += sh1[tok][j] * rW2[j * 8 + e];
    sgl[tok][e] = a;
  }
  __syncthreads();

  // experts (dense, all 8): wave w owns expert w, all 16 tokens (eW1 in bf16)
  {
    int jj = tid & 63, e = tid >> 6;
    float eop[16];
#pragma unroll
    for (int t = 0; t < 16; ++t) eop[t] = 0.f;
#pragma unroll
    for (int jr = 0; jr < 2; ++jr) {
      int j = jj * 4 + jr * 256;
      float4 bb = *(const float4*)(eb1 + e * 512 + j);
      float4 a[16];
#pragma unroll
      for (int t = 0; t < 16; ++t) a[t] = bb;
      const ushort4* wp = (const ushort4*)(eW1b + (size_t)e * 64 * 512 + j);
#pragma unroll 4
      for (int m = 0; m < 64; ++m) {
        ushort4 wu = wp[(size_t)m * 128];
        float wx = b2f(wu.x), wy = b2f(wu.y), wz = b2f(wu.z), ww = b2f(wu.w);
#pragma unroll
        for (int t = 0; t < 16; ++t) {
          float c = sc[t][m];
          a[t].x += wx * c; a[t].y += wy * c;
          a[t].z += wz * c; a[t].w += ww * c;
        }
      }
      float4 w2 = *(const float4*)(eW2 + e * 512 + j);
#pragma unroll
      for (int t = 0; t < 16; ++t)
        eop[t] += ftanh(a[t].x) * w2.x + ftanh(a[t].y) * w2.y +
                  ftanh(a[t].z) * w2.z + ftanh(a[t].w) * w2.w;
    }
#pragma unroll
    for (int t = 0; t < 16; ++t) {
#pragma unroll
      for (int off = 32; off > 0; off >>= 1) eop[t] += __shfl_down(eop[t], off);
    }
    if (jj == 0) {
      float b2 = eb2[e];
#pragma unroll
      for (int t = 0; t < 16; ++t) seo[t][e] = eop[t] + b2;
    }
  }
  __syncthreads();

  // softmax + top-2 + y (one thread per token)
  if (tid < 16) {
    int tok = tid;
    float mx = sgl[tok][0];
#pragma unroll
    for (int e = 1; e < 8; ++e) mx = fmaxf(mx, sgl[tok][e]);
#pragma unroll
    for (int e = 0; e < 8; ++e) sgl[tok][e] = __expf(sgl[tok][e] - mx);  // overwrite with exp
    int i0 = 0;
#pragma unroll
    for (int e = 1; e < 8; ++e) if (sgl[tok][e] > sgl[tok][i0]) i0 = e;
    int i1 = (i0 == 0) ? 1 : 0;
#pragma unroll
    for (int e = 0; e < 8; ++e) if (e != i0 && sgl[tok][e] > sgl[tok][i1]) i1 = e;
    float g0 = sgl[tok][i0], g1 = sgl[tok][i1];
    sy[tok] = (g0 * seo[tok][i0] + g1 * seo[tok][i1]) / (g0 + g1);
  }
  __syncthreads();

  // rate = sigmoid(y * csum + c2s_b)  -> bf16 [16 tok x 1024]
  for (int i = tid; i < 16 * 1024; i += 512) {
    int tok = i >> 10, h = i & 1023;
    float r = fsig(sy[tok] * csum[h] + c2sb[h]);
    rate[(size_t)(t0 + tok) * 1024 + h] = __float2bfloat16(r);
  }
}

// ---------------- launch ----------------
extern "C" void kernel_launch(void* const* d_in, const int* in_sizes, int n_in,
                              void* d_out, int out_size, void* d_ws, size_t ws_size,
                              hipStream_t stream) {
  (void)in_sizes; (void)n_in; (void)out_size; (void)ws_size;
  const int*   ids   = (const int*)d_in[0];
  const float* emb   = (const float*)d_in[1];
  const float* enc_W = (const float*)d_in[2];
  const float* enc_b = (const float*)d_in[3];
  const float* s2c_W = (const float*)d_in[4];
  const float* s2c_b = (const float*)d_in[5];
  const float* rW1   = (const float*)d_in[6];
  const float* rb1   = (const float*)d_in[7];
  const float* rW2   = (const float*)d_in[8];
  const float* rb2   = (const float*)d_in[9];
  const float* eW1   = (const float*)d_in[10];
  const float* eb1   = (const float*)d_in[11];
  const float* eW2   = (const float*)d_in[12];
  const float* eb2   = (const float*)d_in[13];
  const float* c2s_W = (const float*)d_in[14];
  const float* c2s_b = (const float*)d_in[15];
  const float* dec_W = (const float*)d_in[16];
  const float* dec_b = (const float*)d_in[17];
  const float* out_W = (const float*)d_in[18];
  const float* out_b = (const float*)d_in[19];
  float* out = (float*)d_out;

  char* ws = (char*)d_ws;
  size_t off = 0;
  auto alloc = [&](size_t bytes) -> char* {
    off = (off + 255) & ~(size_t)255;
    char* p = ws + off;
    off += bytes;
    return p;
  };
  __hip_bfloat16* outWt = (__hip_bfloat16*)alloc(32000ull * 512 * 2);
  __hip_bfloat16* encWt = (__hip_bfloat16*)alloc(1024ull * 512 * 2);
  __hip_bfloat16* decWt = (__hip_bfloat16*)alloc(512ull * 1024 * 2);
  __hip_bfloat16* eW1b  = (__hip_bfloat16*)alloc(8ull * 64 * 512 * 2);
  __hip_bfloat16* Aenc  = (__hip_bfloat16*)alloc(4096ull * 512 * 2);
  float* u_enc  = (float*)alloc(4096ull * 1024 * 4);
  float* sp_enc = (float*)alloc(4096ull * 1024 * 4);
  float* cont   = (float*)alloc(4096ull * 64 * 4);
  float* csum   = (float*)alloc(1024 * 4);
  float* u_dec  = (float*)alloc(4096ull * 512 * 4);
  __hip_bfloat16* dec = (__hip_bfloat16*)alloc(4096ull * 512 * 2);
  __hip_bfloat16* rate = (__hip_bfloat16*)u_enc;  // reuse: u_enc dead after gif

  // small prep: encWt, decWt, eW1b, gather, csum (3332 blocks)
  prep_k<<<3332, 256, 0, stream>>>(enc_W, encWt, dec_W, decWt,
                                   eW1, eW1b, ids, emb, Aenc, c2s_W, csum);

  // pipeline (out_W transpose fused into gif_enc launch — independent work)
  gemm128_k<<<32 * 8, 256, 0, stream>>>(Aenc, encWt, enc_b, u_enc, 1024, 512, 32);
  gif_trans_k<<<128 + 16000, 256, 0, stream>>>(u_enc, sp_enc, out_W, outWt);
  s2c_k<<<256, 256, 0, stream>>>(sp_enc, s2c_W, s2c_b, cont);
  moe_k<<<256, 512, 0, stream>>>(cont, rW1, rb1, rW2, rb2, eW1b, eb1, eW2, eb2, csum, c2s_b, rate);
  gemm128_k<<<32 * 4, 256, 0, stream>>>(rate, decWt, dec_b, u_dec, 512, 1024, 32);
  gif_scan_k<<<16 * 16, 64, 0, stream>>>(u_dec, dec, 2048, 512, 16);
  gemm256_k<<<2000, 512, 0, stream>>>(dec, outWt, out_b, out, 32000, 512);
}

// Round 19
// 364.947 us; speedup vs baseline: 1.0911x; 1.0322x over previous
//
#include <hip/hip_runtime.h>
#include <hip/hip_bf16.h>
#include <stdint.h>

typedef __attribute__((ext_vector_type(8))) short bf16x8;
typedef __attribute__((ext_vector_type(4))) float f32x4;
typedef __attribute__((address_space(3))) char lds_char_t;

#define LOG2E_X2 2.885390081777927f
#define GIF_A 5.770780163555854f  // 4*log2(e)

__device__ __forceinline__ float fexp2(float x) { return __builtin_amdgcn_exp2f(x); }
__device__ __forceinline__ float frcp(float x)  { return __builtin_amdgcn_rcpf(x); }
__device__ __forceinline__ float gif_spike(float v) {
  return frcp(1.f + fexp2(fmaf(v, -GIF_A, GIF_A)));
}
__device__ __forceinline__ float fsig(float x)  { return frcp(1.f + fexp2(-1.442695040888963f * x)); }
__device__ __forceinline__ float ftanh(float x) { return 1.f - 2.f * frcp(1.f + fexp2(LOG2E_X2 * x)); }
__device__ __forceinline__ float b2f(unsigned short u) {
  return __uint_as_float((unsigned)u << 16);
}

__device__ __forceinline__ void gload_lds16(const void* g, void* l) {
  __builtin_amdgcn_global_load_lds((__attribute__((address_space(1))) void*)(uintptr_t)g,
                                   (__attribute__((address_space(3))) void*)l, 16, 0, 0);
}

__device__ __forceinline__ bf16x8 ds_read_b128_asm(unsigned addr) {
  bf16x8 r;
  asm volatile("ds_read_b128 %0, %1" : "=v"(r) : "v"(addr));
  return r;
}

// ---------------- transpose tile body 32x32 ----------
__device__ __forceinline__ void transpose_body(const float* __restrict__ in,
                                               __hip_bfloat16* __restrict__ out,
                                               int K, int N, int bx, int by,
                                               float (*tile)[33], int tid) {
  int n0 = bx * 32, k0 = by * 32;
  int tx = tid & 31, ty = tid >> 5;  // 256 threads: 32 x 8
#pragma unroll
  for (int i = 0; i < 4; ++i)
    tile[ty + 8 * i][tx] = in[(size_t)(k0 + ty + 8 * i) * N + n0 + tx];
  __syncthreads();
#pragma unroll
  for (int i = 0; i < 4; ++i)
    out[(size_t)(n0 + ty + 8 * i) * K + k0 + tx] = __float2bfloat16(tile[tx][ty + 8 * i]);
}

// ---------------- merged small prep: encWt, decWt, eW1 cast, gather, csum ----------
__global__ __launch_bounds__(256) void prep_k(
    const float* __restrict__ enc_W, __hip_bfloat16* __restrict__ encWt,
    const float* __restrict__ dec_W, __hip_bfloat16* __restrict__ decWt,
    const float* __restrict__ eW1, __hip_bfloat16* __restrict__ eW1b,
    const int* __restrict__ ids, const float* __restrict__ emb,
    __hip_bfloat16* __restrict__ Aenc,
    const float* __restrict__ c2s_W, float* __restrict__ csum) {
  __shared__ float tile[32][33];
  int bid = blockIdx.x;
  int tid = threadIdx.x;
  if (bid < 512) {                        // enc_W [512][1024] -> encWt [1024][512]
    transpose_body(enc_W, encWt, 512, 1024, bid % 32, bid / 32, tile, tid);
  } else if (bid < 1024) {                // dec_W [1024][512] -> decWt [512][1024]
    int b = bid - 512;
    transpose_body(dec_W, decWt, 1024, 512, b % 16, b / 16, tile, tid);
  } else if (bid < 1280) {                // eW1 cast f32->bf16 (262144 elems / 4)
    int i = (bid - 1024) * 256 + tid;
    float4 v = ((const float4*)eW1)[i];
    __hip_bfloat16* o = eW1b + i * 4;
    o[0] = __float2bfloat16(v.x); o[1] = __float2bfloat16(v.y);
    o[2] = __float2bfloat16(v.z); o[3] = __float2bfloat16(v.w);
  } else if (bid < 3328) {                // embedding gather+cast
    int i = (bid - 1280) * 256 + tid;
    int idx = i * 4;
    int row = idx >> 9, col = idx & 511;  // E = 512
    float4 v = *(const float4*)(emb + (size_t)ids[row] * 512 + col);
    __hip_bfloat16* o = Aenc + idx;
    o[0] = __float2bfloat16(v.x); o[1] = __float2bfloat16(v.y);
    o[2] = __float2bfloat16(v.z); o[3] = __float2bfloat16(v.w);
  } else {                                // csum of c2s_W (4 blocks)
    int h = (bid - 3328) * 256 + tid;
    float a = 0.f;
#pragma unroll 8
    for (int m = 0; m < 64; ++m) a += c2s_W[m * 1024 + h];
    csum[h] = a;
  }
}

// ---------------- fused: gif_scan(enc) + out_W transpose (32x32 tiles) --------
__global__ __launch_bounds__(256) void gif_trans_k(
    const float* __restrict__ u, float* __restrict__ sp,
    const float* __restrict__ out_W, __hip_bfloat16* __restrict__ outWt) {
  __shared__ float tile[32][33];
  int bid = blockIdx.x;
  int tid = threadIdx.x;
  if (bid >= 128) {
    int b = bid - 128;
    transpose_body(out_W, outWt, 512, 32000, b % 1000, b / 1000, tile, tid);
    return;
  }
  const int S = 2048, C = 1024;
  int chunk = bid >> 3;                       // 8 blocks per chunk
  int gc = (bid & 7) * 256 + tid;             // 0..2047
  int b = (gc >= C) ? 1 : 0, ch = gc - b * C; // B = 2
  size_t base = (size_t)b * S * C + ch;

  const int CH = 128;
  int s_begin = chunk * CH;
  int sw = (chunk == 0) ? 0 : s_begin - 96;
  int warm = s_begin - sw;            // 0 or 96
  int total = CH + warm;              // 128 or 224
  const float* up = u + base + (size_t)sw * C;

  float v = 0.f;
  float bufA[16], bufB[16];
#pragma unroll
  for (int i = 0; i < 16; ++i) bufA[i] = up[(size_t)i * C];
  for (int t = 0; t < total; t += 32) {
#pragma unroll
    for (int i = 0; i < 16; ++i) bufB[i] = up[(size_t)(t + 16 + i) * C];
#pragma unroll
    for (int i = 0; i < 16; ++i) {
      v = fmaf(0.9f, v, bufA[i]);
      float spk = gif_spike(v);
      v -= spk;
      if (t + i >= warm) sp[base + (size_t)(sw + t + i) * C] = spk;
    }
    if (t + 32 < total) {
#pragma unroll
      for (int i = 0; i < 16; ++i) bufA[i] = up[(size_t)(t + 32 + i) * C];
    }
#pragma unroll
    for (int i = 0; i < 16; ++i) {
      v = fmaf(0.9f, v, bufB[i]);
      float spk = gif_spike(v);
      v -= spk;
      if (t + 16 + i >= warm) sp[base + (size_t)(sw + t + 16 + i) * C] = spk;
    }
  }
}

// ---------------- 128x128 bf16 GEMM (enc/dec): 2-phase dbuf + counted vmcnt + swizzle
__global__ __launch_bounds__(256) void gemm128_k(
    const __hip_bfloat16* __restrict__ A, const __hip_bfloat16* __restrict__ Bt,
    const float* __restrict__ bias, float* __restrict__ C, int N, int K, int GM) {
  __shared__ __align__(16) char smem[65536];  // buf b: A at b*32768, B at +16384

  int nwg = gridDim.x;
  int bid = blockIdx.x;
  int q = nwg >> 3, r = nwg & 7, xcd = bid & 7, bix = bid >> 3;
  int wg = (xcd < r ? xcd * (q + 1) : r * (q + 1) + (xcd - r) * q) + bix;
  int bm = wg % GM, bn = wg / GM;

  int tid = threadIdx.x;
  int lane = tid & 63, w = tid >> 6;
  int wm = w >> 1, wn = w & 1;

  const __hip_bfloat16* gA[4];
  const __hip_bfloat16* gB[4];
#pragma unroll
  for (int i = 0; i < 4; ++i) {
    int c = (w * 4 + i) * 64 + lane;
    int rr = c >> 3, sl = c & 7;
    int sg = sl ^ (rr & 7);
    gA[i] = A + (size_t)(bm * 128 + rr) * K + sg * 8;
    gB[i] = Bt + (size_t)(bn * 128 + rr) * K + sg * 8;
  }

  f32x4 acc[4][4];
#pragma unroll
  for (int i = 0; i < 4; ++i)
#pragma unroll
    for (int j = 0; j < 4; ++j) acc[i][j] = (f32x4){0.f, 0.f, 0.f, 0.f};

  auto stage = [&](int kt, int b) {
    int ko = kt * 64;
    char* baseA = smem + b * 32768;
    char* baseB = baseA + 16384;
#pragma unroll
    for (int i = 0; i < 4; ++i) {
      gload_lds16(gA[i] + ko, baseA + (w * 4 + i) * 1024);
      gload_lds16(gB[i] + ko, baseB + (w * 4 + i) * 1024);
    }
  };

  const int KT = K >> 6;
  stage(0, 0);
  asm volatile("s_waitcnt vmcnt(0)" ::: "memory");
  __builtin_amdgcn_s_barrier();
  int cur = 0;
  for (int kt = 0; kt < KT; ++kt) {
    if (kt + 1 < KT) {
      stage(kt + 1, cur ^ 1);
      asm volatile("s_waitcnt vmcnt(8)" ::: "memory");
    } else {
      asm volatile("s_waitcnt vmcnt(0)" ::: "memory");
    }
    __builtin_amdgcn_s_barrier();
    const char* smA = smem + cur * 32768;
    const char* smB = smA + 16384;
#pragma unroll
    for (int ks = 0; ks < 2; ++ks) {
      bf16x8 af[4], bfr[4];
#pragma unroll
      for (int f = 0; f < 4; ++f) {
        int R = wm * 64 + f * 16 + (lane & 15);
        int R2 = wn * 64 + f * 16 + (lane & 15);
        int sg = ks * 4 + (lane >> 4);
        af[f]  = *(const bf16x8*)(smA + R * 128 + ((sg ^ (R & 7)) << 4));
        bfr[f] = *(const bf16x8*)(smB + R2 * 128 + ((sg ^ (R2 & 7)) << 4));
      }
#pragma unroll
      for (int fm = 0; fm < 4; ++fm)
#pragma unroll
        for (int fn = 0; fn < 4; ++fn)
          acc[fm][fn] = __builtin_amdgcn_mfma_f32_16x16x32_bf16(af[fm], bfr[fn], acc[fm][fn], 0, 0, 0);
    }
    __builtin_amdgcn_sched_barrier(0);
    __builtin_amdgcn_s_barrier();
    cur ^= 1;
  }
  int rbase = bm * 128 + wm * 64 + ((lane >> 4) << 2);
  int cbase = bn * 128 + wn * 64 + (lane & 15);
#pragma unroll
  for (int fn = 0; fn < 4; ++fn) {
    int col = cbase + fn * 16;
    float bs = bias[col];
#pragma unroll
    for (int fm = 0; fm < 4; ++fm) {
      int row = rbase + fm * 16;
#pragma unroll
      for (int rr = 0; rr < 4; ++rr)
        C[(size_t)(row + rr) * N + col] = acc[fm][fn][rr] + bs;
    }
  }
}

// ---------------- 256x256 bf16 GEMM (out, M=4096 N=32000 K=512) — r16 version ------
// 8 waves, 128x64 wave tiles, 2 waves/SIMD. Whole-tile-ahead staging + vmcnt(8);
// within-wave lgkmcnt(12) split; LDS-transpose epilogue; NON-TEMPORAL C stores
// (terminal output only — nt on intermediates was a measured regression, r18).
__global__ __launch_bounds__(512, 2) void gemm256_k(
    const __hip_bfloat16* __restrict__ A, const __hip_bfloat16* __restrict__ Bt,
    const float* __restrict__ bias, float* __restrict__ C, int N, int K) {
  __shared__ __align__(16) char smem[131072];  // buf b: A at b*65536 (32KB), B at +32768

  int nwg = gridDim.x;
  int bid = blockIdx.x;
  int q = nwg >> 3, r = nwg & 7, xcd = bid & 7, bix = bid >> 3;
  int wg = (xcd < r ? xcd * (q + 1) : r * (q + 1) + (xcd - r) * q) + bix;
  // supertile decode: stripe(8bm) -> group(5bn x 8bm, bm-fast)
  int S  = wg / 1000;         // 0..1
  int rr_ = wg - S * 1000;
  int g  = rr_ / 40;          // 0..24
  int t  = rr_ - g * 40;      // 0..39
  int bn = g * 5 + (t >> 3);  // 0..124
  int bm = S * 8 + (t & 7);   // 0..15

  int tid = threadIdx.x;
  int lane = tid & 63, w = tid >> 6;      // 8 waves
  int wm = w >> 2, wn = w & 3;            // 2 x 4 wave grid; wave tile 128x64

  int offA[4], offB[4];
#pragma unroll
  for (int i = 0; i < 4; ++i) {
    int c = (w * 4 + i) * 64 + lane;      // 0..2047
    int rw = c >> 3, sl = c & 7;
    int sg = sl ^ (rw & 7);               // pre-swizzled global k-slot
    offA[i] = (bm * 256 + rw) * K + sg * 8;
    offB[i] = rw * K + sg * 8;            // bn folded into base pointer
  }
  const __hip_bfloat16* Bb = Bt + (size_t)(bn * 256) * K;

  f32x4 acc[8][4];
#pragma unroll
  for (int i = 0; i < 8; ++i)
#pragma unroll
    for (int j = 0; j < 4; ++j) acc[i][j] = (f32x4){0.f, 0.f, 0.f, 0.f};

  auto stage = [&](int kt, int b) {
    int ko = kt * 64;
    char* baseA = smem + b * 65536;
    char* baseB = baseA + 32768;
#pragma unroll
    for (int i = 0; i < 4; ++i) {
      gload_lds16(A + offA[i] + ko, baseA + (w * 4 + i) * 1024);
      gload_lds16(Bb + offB[i] + ko, baseB + (w * 4 + i) * 1024);
    }
  };

  unsigned sbase = (unsigned)(uintptr_t)(lds_char_t*)smem;

  const int KT = K >> 6;
  stage(0, 0);
  int cur = 0;
  for (int kt = 0; kt < KT; ++kt) {
    if (kt + 1 < KT) {
      stage(kt + 1, cur ^ 1);                           // 8 loads in flight
      asm volatile("s_waitcnt vmcnt(8)" ::: "memory");  // wait only for tile kt's 8
    } else {
      asm volatile("s_waitcnt vmcnt(0)" ::: "memory");
    }
    __builtin_amdgcn_s_barrier();                        // LDS[cur] ready for all waves
    unsigned aA = sbase + cur * 65536;
    unsigned aB = aA + 32768;
    int sg0 = (lane >> 4);
    int sg1 = 4 + (lane >> 4);

    bf16x8 b0[4], b1[4], a0a[4], a0b[4], a1a[4], a1b[4];
    // ---- issue all 24 ds_reads (volatile: program order preserved) ----
#pragma unroll
    for (int f = 0; f < 4; ++f) {
      int R2 = wn * 64 + f * 16 + (lane & 15);
      b0[f] = ds_read_b128_asm(aB + R2 * 128 + ((sg0 ^ (R2 & 7)) << 4));
    }
#pragma unroll
    for (int f = 0; f < 4; ++f) {
      int R = wm * 128 + f * 16 + (lane & 15);
      a0a[f] = ds_read_b128_asm(aA + R * 128 + ((sg0 ^ (R & 7)) << 4));
    }
#pragma unroll
    for (int f = 0; f < 4; ++f) {
      int R = wm * 128 + (f + 4) * 16 + (lane & 15);
      a0b[f] = ds_read_b128_asm(aA + R * 128 + ((sg0 ^ (R & 7)) << 4));
    }
#pragma unroll
    for (int f = 0; f < 4; ++f) {
      int R2 = wn * 64 + f * 16 + (lane & 15);
      b1[f] = ds_read_b128_asm(aB + R2 * 128 + ((sg1 ^ (R2 & 7)) << 4));
    }
#pragma unroll
    for (int f = 0; f < 4; ++f) {
      int R = wm * 128 + f * 16 + (lane & 15);
      a1a[f] = ds_read_b128_asm(aA + R * 128 + ((sg1 ^ (R & 7)) << 4));
    }
#pragma unroll
    for (int f = 0; f < 4; ++f) {
      int R = wm * 128 + (f + 4) * 16 + (lane & 15);
      a1b[f] = ds_read_b128_asm(aA + R * 128 + ((sg1 ^ (R & 7)) << 4));
    }
    // ---- ks0 MFMA while ks1 reads drain ----
    asm volatile("s_waitcnt lgkmcnt(12)" ::: "memory");  // first 12 (ks0) complete
    __builtin_amdgcn_sched_barrier(0);
    __builtin_amdgcn_s_setprio(1);
#pragma unroll
    for (int fm = 0; fm < 4; ++fm)
#pragma unroll
      for (int fn = 0; fn < 4; ++fn)
        acc[fm][fn] = __builtin_amdgcn_mfma_f32_16x16x32_bf16(a0a[fm], b0[fn], acc[fm][fn], 0, 0, 0);
#pragma unroll
    for (int fm = 0; fm < 4; ++fm)
#pragma unroll
      for (int fn = 0; fn < 4; ++fn)
        acc[fm + 4][fn] = __builtin_amdgcn_mfma_f32_16x16x32_bf16(a0b[fm], b0[fn], acc[fm + 4][fn], 0, 0, 0);
    __builtin_amdgcn_s_setprio(0);
    // ---- ks1 MFMA ----
    asm volatile("s_waitcnt lgkmcnt(0)" ::: "memory");
    __builtin_amdgcn_sched_barrier(0);
    __builtin_amdgcn_s_setprio(1);
#pragma unroll
    for (int fm = 0; fm < 4; ++fm)
#pragma unroll
      for (int fn = 0; fn < 4; ++fn)
        acc[fm][fn] = __builtin_amdgcn_mfma_f32_16x16x32_bf16(a1a[fm], b1[fn], acc[fm][fn], 0, 0, 0);
#pragma unroll
    for (int fm = 0; fm < 4; ++fm)
#pragma unroll
      for (int fn = 0; fn < 4; ++fn)
        acc[fm + 4][fn] = __builtin_amdgcn_mfma_f32_16x16x32_bf16(a1b[fm], b1[fn], acc[fm + 4][fn], 0, 0, 0);
    __builtin_amdgcn_s_setprio(0);
    __builtin_amdgcn_sched_barrier(0);
    __builtin_amdgcn_s_barrier();                        // all waves done reading cur
    cur ^= 1;
  }

  // ---- epilogue: LDS-transpose -> contiguous NON-TEMPORAL dwordx4 stores ----
  float* sC = (float*)smem;
#pragma unroll
  for (int h = 0; h < 2; ++h) {
    __syncthreads();            // smem free (main loop done / prev half read done)
    if (wm == h) {
#pragma unroll
      for (int fn = 0; fn < 4; ++fn) {
        int lc = wn * 64 + fn * 16 + (lane & 15);
        float bs = bias[bn * 256 + lc];
#pragma unroll
        for (int fm = 0; fm < 8; ++fm)
#pragma unroll
          for (int rw = 0; rw < 4; ++rw) {
            int lr = fm * 16 + ((lane >> 4) << 2) + rw;  // 0..127 local row
            sC[lr * 256 + lc] = acc[fm][fn][rw] + bs;
          }
      }
    }
    __syncthreads();
    // 512 threads stream 128 rows x 1KB contiguous, nt (no L2 allocation)
#pragma unroll
    for (int it = 0; it < 16; ++it) {
      int lr = it * 8 + w;
      int lc = (tid & 63) * 4;
      f32x4 v = *(f32x4*)&sC[lr * 256 + lc];
      __builtin_nontemporal_store(v, (f32x4*)(C + (size_t)(bm * 256 + h * 128 + lr) * N + bn * 256 + lc));
    }
  }
}

// ---------------- GIF scan (dec), chunk-parallel, 64-thread blocks ----------------
__global__ void gif_scan_k(const float* __restrict__ u, __hip_bfloat16* __restrict__ out,
                           int S, int C, int bpc) {
  int chunk = blockIdx.x / bpc;
  int gc = (blockIdx.x - chunk * bpc) * 64 + threadIdx.x;
  int b = (gc >= C) ? 1 : 0, ch = gc - b * C;  // B = 2
  size_t base = (size_t)b * S * C + ch;

  const int CH = 128;
  int s_begin = chunk * CH;
  int sw = (chunk == 0) ? 0 : s_begin - 96;
  int warm = s_begin - sw;
  int total = CH + warm;
  const float* up = u + base + (size_t)sw * C;

  float v = 0.f;
  float bufA[16], bufB[16];
#pragma unroll
  for (int i = 0; i < 16; ++i) bufA[i] = up[(size_t)i * C];
  for (int t = 0; t < total; t += 32) {
#pragma unroll
    for (int i = 0; i < 16; ++i) bufB[i] = up[(size_t)(t + 16 + i) * C];
#pragma unroll
    for (int i = 0; i < 16; ++i) {
      v = fmaf(0.9f, v, bufA[i]);
      float spk = gif_spike(v);
      v -= spk;
      if (t + i >= warm) out[base + (size_t)(sw + t + i) * C] = __float2bfloat16(spk);
    }
    if (t + 32 < total) {
#pragma unroll
      for (int i = 0; i < 16; ++i) bufA[i] = up[(size_t)(t + 32 + i) * C];
    }
#pragma unroll
    for (int i = 0; i < 16; ++i) {
      v = fmaf(0.9f, v, bufB[i]);
      float spk = gif_spike(v);
      v -= spk;
      if (t + 16 + i >= warm) out[base + (size_t)(sw + t + 16 + i) * C] = __float2bfloat16(spk);
    }
  }
}

// ---------------- s2c: cont[4096,64] = sp[4096,1024] @ W[1024,64] + b ----------------
__global__ void s2c_k(const float* __restrict__ sp, const float* __restrict__ W,
                      const float* __restrict__ b, float* __restrict__ cont) {
  int n = threadIdx.x & 63, tg = threadIdx.x >> 6;
  int tok0 = blockIdx.x * 16 + tg * 4;
  const float* s0 = sp + (size_t)tok0 * 1024;
  float a0 = 0, a1 = 0, a2 = 0, a3 = 0;
#pragma unroll 8
  for (int k = 0; k < 1024; ++k) {
    float w = W[k * 64 + n];
    a0 += s0[k] * w;
    a1 += s0[k + 1024] * w;
    a2 += s0[k + 2048] * w;
    a3 += s0[k + 3072] * w;
  }
  float bb = b[n];
  cont[(size_t)(tok0 + 0) * 64 + n] = a0 + bb;
  cont[(size_t)(tok0 + 1) * 64 + n] = a1 + bb;
  cont[(size_t)(tok0 + 2) * 64 + n] = a2 + bb;
  cont[(size_t)(tok0 + 3) * 64 + n] = a3 + bb;
}

// ---------------- fused router + experts + y + rate (16 tokens/block, 8 waves) ------
__global__ __launch_bounds__(512) void moe_k(
    const float* __restrict__ cont,
    const float* __restrict__ rW1, const float* __restrict__ rb1,
    const float* __restrict__ rW2, const float* __restrict__ rb2,
    const __hip_bfloat16* __restrict__ eW1b, const float* __restrict__ eb1,
    const float* __restrict__ eW2, const float* __restrict__ eb2,
    const float* __restrict__ csum, const float* __restrict__ c2sb,
    __hip_bfloat16* __restrict__ rate) {
  __shared__ float sc[16][65];
  __shared__ float sh1[16][65];
  __shared__ float sgl[16][8];
  __shared__ float seo[16][8];
  __shared__ float sy[16];
  int tid = threadIdx.x;
  int t0 = blockIdx.x * 16;

  for (int i = tid; i < 1024; i += 512) sc[i >> 6][i & 63] = cont[(size_t)t0 * 64 + i];
  __syncthreads();

  // router layer 1: h1 = tanh(cont @ rW1 + rb1)   (16 tok x 64 units; threads 0..255)
  if (tid < 256) {
    int tok = tid >> 4, u0 = tid & 15;
#pragma unroll
    for (int uu = 0; uu < 4; ++uu) {
      int un = u0 + 16 * uu;
      float a = rb1[un];
#pragma unroll 8
      for (int m = 0; m < 64; ++m) a += sc[tok][m] * rW1[m * 64 + un];
      sh1[tok][un] = ftanh(a);
    }
  }
  __syncthreads();
  // router layer 2: gl = h1 @ rW2 + rb2  (16 tok x 8 experts)
  if (tid < 128) {
    int tok = tid >> 3, e = tid & 7;
    float a = rb2[e];
#pragma unroll 8
    for (int j = 0; j < 64; ++j) a += sh1[tok][j] * rW2[j * 8 + e];
    sgl[tok][e] = a;
  }
  __syncthreads();

  // experts (dense, all 8): wave w owns expert w, all 16 tokens (eW1 in bf16)
  {
    int jj = tid & 63, e = tid >> 6;
    float eop[16];
#pragma unroll
    for (int t = 0; t < 16; ++t) eop[t] = 0.f;
#pragma unroll
    for (int jr = 0; jr < 2; ++jr) {
      int j = jj * 4 + jr * 256;
      float4 bb = *(const float4*)(eb1 + e * 512 + j);
      float4 a[16];
#pragma unroll
      for (int t = 0; t < 16; ++t) a[t] = bb;
      const ushort4* wp = (const ushort4*)(eW1b + (size_t)e * 64 * 512 + j);
#pragma unroll 4
      for (int m = 0; m < 64; ++m) {
        ushort4 wu = wp[(size_t)m * 128];
        float wx = b2f(wu.x), wy = b2f(wu.y), wz = b2f(wu.z), ww = b2f(wu.w);
#pragma unroll
        for (int t = 0; t < 16; ++t) {
          float c = sc[t][m];
          a[t].x += wx * c; a[t].y += wy * c;
          a[t].z += wz * c; a[t].w += ww * c;
        }
      }
      float4 w2 = *(const float4*)(eW2 + e * 512 + j);
#pragma unroll
      for (int t = 0; t < 16; ++t)
        eop[t] += ftanh(a[t].x) * w2.x + ftanh(a[t].y) * w2.y +
                  ftanh(a[t].z) * w2.z + ftanh(a[t].w) * w2.w;
    }
#pragma unroll
    for (int t = 0; t < 16; ++t) {
#pragma unroll
      for (int off = 32; off > 0; off >>= 1) eop[t] += __shfl_down(eop[t], off);
    }
    if (jj == 0) {
      float b2 = eb2[e];
#pragma unroll
      for (int t = 0; t < 16; ++t) seo[t][e] = eop[t] + b2;
    }
  }
  __syncthreads();

  // softmax + top-2 + y (one thread per token)
  if (tid < 16) {
    int tok = tid;
    float mx = sgl[tok][0];
#pragma unroll
    for (int e = 1; e < 8; ++e) mx = fmaxf(mx, sgl[tok][e]);
#pragma unroll
    for (int e = 0; e < 8; ++e) sgl[tok][e] = __expf(sgl[tok][e] - mx);  // overwrite with exp
    int i0 = 0;
#pragma unroll
    for (int e = 1; e < 8; ++e) if (sgl[tok][e] > sgl[tok][i0]) i0 = e;
    int i1 = (i0 == 0) ? 1 : 0;
#pragma unroll
    for (int e = 0; e < 8; ++e) if (e != i0 && sgl[tok][e] > sgl[tok][i1]) i1 = e;
    float g0 = sgl[tok][i0], g1 = sgl[tok][i1];
    sy[tok] = (g0 * seo[tok][i0] + g1 * seo[tok][i1]) / (g0 + g1);
  }
  __syncthreads();

  // rate = sigmoid(y * csum + c2s_b)  -> bf16 [16 tok x 1024]
  for (int i = tid; i < 16 * 1024; i += 512) {
    int tok = i >> 10, h = i & 1023;
    float r = fsig(sy[tok] * csum[h] + c2sb[h]);
    rate[(size_t)(t0 + tok) * 1024 + h] = __float2bfloat16(r);
  }
}

// ---------------- launch ----------------
extern "C" void kernel_launch(void* const* d_in, const int* in_sizes, int n_in,
                              void* d_out, int out_size, void* d_ws, size_t ws_size,
                              hipStream_t stream) {
  (void)in_sizes; (void)n_in; (void)out_size; (void)ws_size;
  const int*   ids   = (const int*)d_in[0];
  const float* emb   = (const float*)d_in[1];
  const float* enc_W = (const float*)d_in[2];
  const float* enc_b = (const float*)d_in[3];
  const float* s2c_W = (const float*)d_in[4];
  const float* s2c_b = (const float*)d_in[5];
  const float* rW1   = (const float*)d_in[6];
  const float* rb1   = (const float*)d_in[7];
  const float* rW2   = (const float*)d_in[8];
  const float* rb2   = (const float*)d_in[9];
  const float* eW1   = (const float*)d_in[10];
  const float* eb1   = (const float*)d_in[11];
  const float* eW2   = (const float*)d_in[12];
  const float* eb2   = (const float*)d_in[13];
  const float* c2s_W = (const float*)d_in[14];
  const float* c2s_b = (const float*)d_in[15];
  const float* dec_W = (const float*)d_in[16];
  const float* dec_b = (const float*)d_in[17];
  const float* out_W = (const float*)d_in[18];
  const float* out_b = (const float*)d_in[19];
  float* out = (float*)d_out;

  char* ws = (char*)d_ws;
  size_t off = 0;
  auto alloc = [&](size_t bytes) -> char* {
    off = (off + 255) & ~(size_t)255;
    char* p = ws + off;
    off += bytes;
    return p;
  };
  __hip_bfloat16* outWt = (__hip_bfloat16*)alloc(32000ull * 512 * 2);
  __hip_bfloat16* encWt = (__hip_bfloat16*)alloc(1024ull * 512 * 2);
  __hip_bfloat16* decWt = (__hip_bfloat16*)alloc(512ull * 1024 * 2);
  __hip_bfloat16* eW1b  = (__hip_bfloat16*)alloc(8ull * 64 * 512 * 2);
  __hip_bfloat16* Aenc  = (__hip_bfloat16*)alloc(4096ull * 512 * 2);
  float* u_enc  = (float*)alloc(4096ull * 1024 * 4);
  float* sp_enc = (float*)alloc(4096ull * 1024 * 4);
  float* cont   = (float*)alloc(4096ull * 64 * 4);
  float* csum   = (float*)alloc(1024 * 4);
  float* u_dec  = (float*)alloc(4096ull * 512 * 4);
  __hip_bfloat16* dec = (__hip_bfloat16*)alloc(4096ull * 512 * 2);
  __hip_bfloat16* rate = (__hip_bfloat16*)u_enc;  // reuse: u_enc dead after gif

  // small prep: encWt, decWt, eW1b, gather, csum (3332 blocks)
  prep_k<<<3332, 256, 0, stream>>>(enc_W, encWt, dec_W, decWt,
                                   eW1, eW1b, ids, emb, Aenc, c2s_W, csum);

  // pipeline (out_W transpose fused into gif_enc launch — independent work)
  gemm128_k<<<32 * 8, 256, 0, stream>>>(Aenc, encWt, enc_b, u_enc, 1024, 512, 32);
  gif_trans_k<<<128 + 16000, 256, 0, stream>>>(u_enc, sp_enc, out_W, outWt);
  s2c_k<<<256, 256, 0, stream>>>(sp_enc, s2c_W, s2c_b, cont);
  moe_k<<<256, 512, 0, stream>>>(cont, rW1, rb1, rW2, rb2, eW1b, eb1, eW2, eb2, csum, c2s_b, rate);
  gemm128_k<<<32 * 4, 256, 0, stream>>>(rate, decWt, dec_b, u_dec, 512, 1024, 32);
  gif_scan_k<<<16 * 16, 64, 0, stream>>>(u_dec, dec, 2048, 512, 16);
  gemm256_k<<<2000, 512, 0, stream>>>(dec, outWt, out_b, out, 32000, 512);
}